// Round 17
// baseline (181.318 us; speedup 1.0000x reference)
//
#include <hip/hip_runtime.h>
#include <math.h>

#define B_ 16
#define T_ 24
#define G_ 384
#define N_ 300
#define E_ 9600
#define H_ 3
#define F_ 8
#define HF_ 24
#define GRUH_ 16
#define OUTB_ 7200   // NUM_AIRPORTS * HORIZON
#define NW_ 16       // waves in csr block
#define TPB_ 640     // gat block threads (10 waves)

// ====== K1: CSR build with per-wave sub-histograms (validated R12) ==================
__global__ __launch_bounds__(1024) void csr_kernel(
    const int* __restrict__ src, const int* __restrict__ dst,
    int* __restrict__ rp, unsigned* __restrict__ pk)
{
    __shared__ int cnt[NW_ * N_];
    __shared__ int tot[N_];
    __shared__ int rps[N_ + 1];
    const int tid = threadIdx.x;
    const int w = tid >> 6;

    for (int i = tid; i < NW_ * N_; i += 1024) cnt[i] = 0;
    __syncthreads();
    for (int i = tid; i < E_; i += 1024) atomicAdd(&cnt[w * N_ + dst[i]], 1);
    __syncthreads();
    if (tid < N_) {
        int run = 0;
        #pragma unroll
        for (int k = 0; k < NW_; ++k) {
            int t = cnt[k * N_ + tid];
            cnt[k * N_ + tid] = run;
            run += t;
        }
        tot[tid] = run;
    }
    __syncthreads();
    if (tid < 64) {
        int base = 0;
        for (int c = 0; c < 5; ++c) {
            int i = c * 64 + tid;
            int orig = (i < N_) ? tot[i] : 0;
            int v = orig;
            #pragma unroll
            for (int o = 1; o < 64; o <<= 1) {
                int u = __shfl_up(v, o, 64);
                if (tid >= o) v += u;
            }
            if (i < N_) rps[i] = base + v - orig;
            base += __shfl(v, 63, 64);
        }
        if (tid == 0) rps[N_] = base;
    }
    __syncthreads();
    for (int i = tid; i <= N_; i += 1024) rp[i] = rps[i];
    for (int i = tid; i < E_; i += 1024) {
        int d = dst[i];
        int pos = rps[d] + atomicAdd(&cnt[w * N_ + d], 1);
        pk[pos] = (unsigned)i | ((unsigned)src[i] << 17);
    }
}

// ====== K2: EdgeGAT, 1 block/graph: coalesced staging, ALL gathers in LDS ===========
__global__ __launch_bounds__(TPB_) void gat_kernel(
    const float* __restrict__ x, const float* __restrict__ ew,
    const float* __restrict__ Wn, const float* __restrict__ We,
    const float* __restrict__ al, const float* __restrict__ ar,
    const float* __restrict__ ae,
    const int* __restrict__ rp_g, const unsigned* __restrict__ pk_g,
    float* __restrict__ S)
{
    __shared__ float ews[E_];
    __shared__ unsigned pkl[E_];
    __shared__ float xs[N_];
    __shared__ int rp_l[N_ + 1];
    __shared__ float cf[9];
    __shared__ float Sred[10][3];

    const int g = blockIdx.x;
    const int tid = threadIdx.x;
    const long base_e = (long)g * E_;

    const float4* ew4 = (const float4*)(ew + base_e);
    float4* ews4 = (float4*)ews;
    for (int i = tid; i < E_ / 4; i += TPB_) ews4[i] = ew4[i];
    const uint4* pk4 = (const uint4*)pk_g;
    uint4* pkl4 = (uint4*)pkl;
    for (int i = tid; i < E_ / 4; i += TPB_) pkl4[i] = pk4[i];
    for (int i = tid; i < N_; i += TPB_) xs[i] = x[g * N_ + i];
    for (int i = tid; i <= N_; i += TPB_) rp_l[i] = rp_g[i];
    if (tid < H_) {
        int h = tid;
        float cl = 0.f, cr = 0.f, ce = 0.f;
        #pragma unroll
        for (int f = 0; f < F_; ++f) {
            float wn = Wn[h * F_ + f];
            cl += wn * al[h * F_ + f];
            cr += wn * ar[h * F_ + f];
            ce += We[h * F_ + f] * ae[h * F_ + f];
        }
        cf[h] = cl; cf[3 + h] = cr; cf[6 + h] = ce;
    }
    __syncthreads();

    float n0 = 0.f, d0 = 0.f, n1 = 0.f, d1 = 0.f, n2 = 0.f, d2 = 0.f;
    if (tid < 2 * N_) {
        const int n = tid >> 1;
        const int half = tid & 1;
        const float xd = xs[n];
        const float c0l = cf[0], c1l = cf[1], c2l = cf[2];
        const float c0r = cf[3], c1r = cf[4], c2r = cf[5];
        const float c0e = cf[6], c1e = cf[7], c2e = cf[8];
        const int p1 = rp_l[n + 1];
        for (int p = rp_l[n] + half; p < p1; p += 2) {
            unsigned pkv = pkl[p];
            float w = ews[pkv & 0x1FFFFu];
            float xsv = xs[pkv >> 17];
            float e0 = fmaf(xsv, c0l, fmaf(xd, c0r, w * c0e)); e0 = e0 > 0.f ? e0 : 0.2f * e0;
            float e1 = fmaf(xsv, c1l, fmaf(xd, c1r, w * c1e)); e1 = e1 > 0.f ? e1 : 0.2f * e1;
            float e2 = fmaf(xsv, c2l, fmaf(xd, c2r, w * c2e)); e2 = e2 > 0.f ? e2 : 0.2f * e2;
            float p0 = __expf(e0), pe1 = __expf(e1), pe2 = __expf(e2);
            d0 += p0;  n0 += p0 * xsv;
            d1 += pe1; n1 += pe1 * xsv;
            d2 += pe2; n2 += pe2 * xsv;
        }
    }
    n0 += __shfl_xor(n0, 1); d0 += __shfl_xor(d0, 1);
    n1 += __shfl_xor(n1, 1); d1 += __shfl_xor(d1, 1);
    n2 += __shfl_xor(n2, 1); d2 += __shfl_xor(d2, 1);
    float a0 = 0.f, a1 = 0.f, a2 = 0.f;
    if (tid < 2 * N_ && (tid & 1) == 0) {
        a0 = d0 > 0.f ? n0 / d0 : 0.f;
        a1 = d1 > 0.f ? n1 / d1 : 0.f;
        a2 = d2 > 0.f ? n2 / d2 : 0.f;
    }
    for (int o = 32; o; o >>= 1) {
        a0 += __shfl_down(a0, o);
        a1 += __shfl_down(a1, o);
        a2 += __shfl_down(a2, o);
    }
    const int wave = tid >> 6, lane = tid & 63;
    if (lane == 0) { Sred[wave][0] = a0; Sred[wave][1] = a1; Sred[wave][2] = a2; }
    __syncthreads();
    if (tid < 3) {
        float s = 0.f;
        #pragma unroll
        for (int w2 = 0; w2 < TPB_ / 64; ++w2) s += Sred[w2][tid];
        S[g * 3 + tid] = s;
    }
}

// ====== K3: FC with replicated-GRU prologue (CPB=1 S layout) ========================
__global__ __launch_bounds__(256) void fc_kernel(
    const float* __restrict__ S, const float* __restrict__ Wn,
    const float* __restrict__ gb, const float* __restrict__ Wih,
    const float* __restrict__ bih, const float* __restrict__ Whh,
    const float* __restrict__ bhh, const float* __restrict__ Wfc,
    const float* __restrict__ bfc, float* __restrict__ out)
{
    __shared__ float S2[2][T_][H_];
    __shared__ float hS[2][GRUH_];
    const int tid = threadIdx.x;
    const int idx0 = blockIdx.x * 256;
    const int b0 = idx0 / OUTB_;

    if (tid < 2 * T_ * H_) {
        const int grp = tid / (T_ * H_);
        const int rem = tid - grp * (T_ * H_);
        const int t = rem / H_, h = rem - t * H_;
        const int bb = b0 + grp;
        float s = 0.f;
        if (bb < B_) s = S[(bb * T_ + t) * H_ + h];
        S2[grp][t][h] = s * (1.0f / N_);
    }
    __syncthreads();

    if (tid < 64) {
        const int grp = tid >> 4;
        const int u = tid & 15;
        const int gbase = tid & ~15;
        const bool active = (grp < 2) && (b0 + grp < B_);
        const int sgrp = active ? grp : 0;

        float whr[GRUH_], whz[GRUH_], whn[GRUH_];
        #pragma unroll
        for (int k = 0; k < GRUH_; ++k) {
            whr[k] = Whh[u * GRUH_ + k];
            whz[k] = Whh[(16 + u) * GRUH_ + k];
            whn[k] = Whh[(32 + u) * GRUH_ + k];
        }
        const float bhr = bhh[u], bhz = bhh[16 + u], bhn = bhh[32 + u];

        float A[3][3], C[3];
        #pragma unroll
        for (int r = 0; r < 3; ++r) {
            const int j = r * 16 + u;
            float cc = bih[j];
            A[r][0] = A[r][1] = A[r][2] = 0.f;
            #pragma unroll
            for (int k = 0; k < HF_; ++k) {
                float wk = Wih[j * HF_ + k];
                cc += wk * gb[k];
                A[r][k >> 3] += wk * Wn[k];
            }
            C[r] = cc;
        }

        float h = 0.f;
        for (int t = 0; t < T_; ++t) {
            float S0 = S2[sgrp][t][0], S1 = S2[sgrp][t][1], Sv2 = S2[sgrp][t][2];
            float gr = C[0] + A[0][0] * S0 + A[0][1] * S1 + A[0][2] * Sv2;
            float gz = C[1] + A[1][0] * S0 + A[1][1] * S1 + A[1][2] * Sv2;
            float gn = C[2] + A[2][0] * S0 + A[2][1] * S1 + A[2][2] * Sv2;
            float hr = bhr, hz = bhz, hn = bhn;
            #pragma unroll
            for (int k = 0; k < GRUH_; ++k) {
                float hk = __shfl(h, gbase + k, 64);
                hr += whr[k] * hk;
                hz += whz[k] * hk;
                hn += whn[k] * hk;
            }
            float r = 1.f / (1.f + __expf(-(gr + hr)));
            float z = 1.f / (1.f + __expf(-(gz + hz)));
            float nn = tanhf(gn + r * hn);
            h = (1.f - z) * nn + z * h;
        }
        if (active) hS[grp][u] = h;
    }
    __syncthreads();

    const int idx = idx0 + tid;
    if (idx < B_ * OUTB_) {
        const int b = idx / OUTB_, o = idx - b * OUTB_;
        const float4* wr = (const float4*)(Wfc + (long)o * GRUH_);
        const float* hr = hS[b - b0];
        float4 w0 = wr[0], w1 = wr[1], w2 = wr[2], w3 = wr[3];
        float acc = bfc[o];
        acc += hr[0]  * w0.x + hr[1]  * w0.y + hr[2]  * w0.z + hr[3]  * w0.w;
        acc += hr[4]  * w1.x + hr[5]  * w1.y + hr[6]  * w1.z + hr[7]  * w1.w;
        acc += hr[8]  * w2.x + hr[9]  * w2.y + hr[10] * w2.z + hr[11] * w2.w;
        acc += hr[12] * w3.x + hr[13] * w3.y + hr[14] * w3.z + hr[15] * w3.w;
        out[idx] = acc;
    }
}

extern "C" void kernel_launch(void* const* d_in, const int* in_sizes, int n_in,
                              void* d_out, int out_size, void* d_ws, size_t ws_size,
                              hipStream_t stream) {
    const float* x    = (const float*)d_in[0];
    const float* ew   = (const float*)d_in[1];
    const float* Wn   = (const float*)d_in[2];
    const float* We   = (const float*)d_in[3];
    const float* al   = (const float*)d_in[4];
    const float* ar   = (const float*)d_in[5];
    const float* ae   = (const float*)d_in[6];
    const float* gb   = (const float*)d_in[7];
    const float* Wih  = (const float*)d_in[8];
    const float* Whh  = (const float*)d_in[9];
    const float* bih  = (const float*)d_in[10];
    const float* bhh  = (const float*)d_in[11];
    const float* Wfc  = (const float*)d_in[12];
    const float* bfc  = (const float*)d_in[13];
    const int*   src  = (const int*)d_in[14];
    const int*   dst  = (const int*)d_in[15];
    float* out = (float*)d_out;

    // ws layout
    int* rp = (int*)d_ws;                               // [301] (pad to 320)
    unsigned* pk = (unsigned*)(rp + 320);               // [9600]
    float* S = (float*)(pk + E_);                       // [384*3]

    csr_kernel<<<1, 1024, 0, stream>>>(src, dst, rp, pk);
    // DIAGNOSTIC: gat x10 (idempotent). gat+gap = (total_R17 - total_R16) / 9.
    for (int rep = 0; rep < 10; ++rep)
        gat_kernel<<<G_, TPB_, 0, stream>>>(x, ew, Wn, We, al, ar, ae, rp, pk, S);
    fc_kernel<<<(B_ * OUTB_ + 255) / 256, 256, 0, stream>>>(S, Wn, gb, Wih, bih,
                                                            Whh, bhh, Wfc, bfc, out);
}

// Round 20
// 35.508 us; speedup vs baseline: 5.1063x; 5.1063x over previous
//
#include <hip/hip_runtime.h>
#include <math.h>

#define B_ 16
#define T_ 24
#define G_ 384
#define N_ 300
#define E_ 9600
#define H_ 3
#define F_ 8
#define HF_ 24
#define GRUH_ 16
#define OUTB_ 7200   // NUM_AIRPORTS * HORIZON
#define TPB_ 640     // 10 waves
#define NWC_ 10      // per-wave sub-histograms

// ====== K1: EdgeGAT with PER-BLOCK LDS CSR build (no csr dispatch, no global pk) ====
__global__ __launch_bounds__(TPB_) void gat_kernel(
    const float* __restrict__ x, const float* __restrict__ ew,
    const float* __restrict__ Wn, const float* __restrict__ We,
    const float* __restrict__ al, const float* __restrict__ ar,
    const float* __restrict__ ae,
    const int* __restrict__ src, const int* __restrict__ dst,
    float* __restrict__ S)
{
    __shared__ unsigned pkl[E_];        // 38.4 KB: (eid | src<<17) dst-sorted
    __shared__ int cnt[NWC_ * N_];      // 12 KB: per-wave histograms -> prefixes
    __shared__ int tot[N_];
    __shared__ int rps[N_ + 1];
    __shared__ float xs[N_];
    __shared__ float cf[9];
    __shared__ float Sred[NWC_][3];

    const int g = blockIdx.x;
    const int tid = threadIdx.x;
    const int w = tid >> 6;
    const long base_e = (long)g * E_;

    // ---- stage xs / coefficients ----
    for (int i = tid; i < N_; i += TPB_) xs[i] = x[g * N_ + i];
    if (tid < H_) {
        int h = tid;
        float cl = 0.f, cr = 0.f, ce = 0.f;
        #pragma unroll
        for (int f = 0; f < F_; ++f) {
            float wn = Wn[h * F_ + f];
            cl += wn * al[h * F_ + f];
            cr += wn * ar[h * F_ + f];
            ce += We[h * F_ + f] * ae[h * F_ + f];
        }
        cf[h] = cl; cf[3 + h] = cr; cf[6 + h] = ce;
    }

    // ---- per-block CSR build (validated R12 logic, LDS-local) ----
    for (int i = tid; i < NWC_ * N_; i += TPB_) cnt[i] = 0;
    __syncthreads();
    for (int i = tid; i < E_; i += TPB_) atomicAdd(&cnt[w * N_ + dst[i]], 1);
    __syncthreads();
    if (tid < N_) {
        int run = 0;
        #pragma unroll
        for (int k = 0; k < NWC_; ++k) {
            int t = cnt[k * N_ + tid];
            cnt[k * N_ + tid] = run;
            run += t;
        }
        tot[tid] = run;
    }
    __syncthreads();
    if (tid < 64) {                       // wave 0 scans 300 counts in 5 chunks
        int base = 0;
        for (int c = 0; c < 5; ++c) {
            int i = c * 64 + tid;
            int orig = (i < N_) ? tot[i] : 0;
            int v = orig;
            #pragma unroll
            for (int o = 1; o < 64; o <<= 1) {
                int u = __shfl_up(v, o, 64);
                if (tid >= o) v += u;
            }
            if (i < N_) rps[i] = base + v - orig;
            base += __shfl(v, 63, 64);
        }
        if (tid == 0) rps[N_] = base;
    }
    __syncthreads();
    for (int i = tid; i < E_; i += TPB_) {
        int d = dst[i];
        int pos = rps[d] + atomicAdd(&cnt[w * N_ + d], 1);
        pkl[pos] = (unsigned)i | ((unsigned)src[i] << 17);
    }
    __syncthreads();

    // ---- edge loop: 2 threads per node; pkl/xs in LDS, ew direct global ----
    float n0 = 0.f, d0 = 0.f, n1 = 0.f, d1 = 0.f, n2 = 0.f, d2 = 0.f;
    if (tid < 2 * N_) {
        const int n = tid >> 1;
        const int half = tid & 1;
        const float xd = xs[n];
        const float c0l = cf[0], c1l = cf[1], c2l = cf[2];
        const float c0r = cf[3], c1r = cf[4], c2r = cf[5];
        const float c0e = cf[6], c1e = cf[7], c2e = cf[8];
        const int p1 = rps[n + 1];
        for (int p = rps[n] + half; p < p1; p += 2) {
            unsigned pkv = pkl[p];
            float wv = ew[base_e + (pkv & 0x1FFFFu)];
            float xsv = xs[pkv >> 17];
            float e0 = fmaf(xsv, c0l, fmaf(xd, c0r, wv * c0e)); e0 = e0 > 0.f ? e0 : 0.2f * e0;
            float e1 = fmaf(xsv, c1l, fmaf(xd, c1r, wv * c1e)); e1 = e1 > 0.f ? e1 : 0.2f * e1;
            float e2 = fmaf(xsv, c2l, fmaf(xd, c2r, wv * c2e)); e2 = e2 > 0.f ? e2 : 0.2f * e2;
            float p0 = __expf(e0), pe1 = __expf(e1), pe2 = __expf(e2);
            d0 += p0;  n0 += p0 * xsv;
            d1 += pe1; n1 += pe1 * xsv;
            d2 += pe2; n2 += pe2 * xsv;
        }
    }
    n0 += __shfl_xor(n0, 1); d0 += __shfl_xor(d0, 1);
    n1 += __shfl_xor(n1, 1); d1 += __shfl_xor(d1, 1);
    n2 += __shfl_xor(n2, 1); d2 += __shfl_xor(d2, 1);
    float a0 = 0.f, a1 = 0.f, a2 = 0.f;
    if (tid < 2 * N_ && (tid & 1) == 0) {
        a0 = d0 > 0.f ? n0 / d0 : 0.f;
        a1 = d1 > 0.f ? n1 / d1 : 0.f;
        a2 = d2 > 0.f ? n2 / d2 : 0.f;
    }
    for (int o = 32; o; o >>= 1) {
        a0 += __shfl_down(a0, o);
        a1 += __shfl_down(a1, o);
        a2 += __shfl_down(a2, o);
    }
    const int wave = tid >> 6, lane = tid & 63;
    if (lane == 0) { Sred[wave][0] = a0; Sred[wave][1] = a1; Sred[wave][2] = a2; }
    __syncthreads();
    if (tid < 3) {
        float s = 0.f;
        #pragma unroll
        for (int w2 = 0; w2 < NWC_; ++w2) s += Sred[w2][tid];
        S[g * 3 + tid] = s;
    }
}

// ====== K2: FC with replicated-GRU prologue (fast tanh via __expf) ==================
__global__ __launch_bounds__(256) void fc_kernel(
    const float* __restrict__ S, const float* __restrict__ Wn,
    const float* __restrict__ gb, const float* __restrict__ Wih,
    const float* __restrict__ bih, const float* __restrict__ Whh,
    const float* __restrict__ bhh, const float* __restrict__ Wfc,
    const float* __restrict__ bfc, float* __restrict__ out)
{
    __shared__ float S2[2][T_][H_];
    __shared__ float hS[2][GRUH_];
    const int tid = threadIdx.x;
    const int idx0 = blockIdx.x * 256;
    const int b0 = idx0 / OUTB_;

    if (tid < 2 * T_ * H_) {
        const int grp = tid / (T_ * H_);
        const int rem = tid - grp * (T_ * H_);
        const int t = rem / H_, h = rem - t * H_;
        const int bb = b0 + grp;
        float s = 0.f;
        if (bb < B_) s = S[(bb * T_ + t) * H_ + h];
        S2[grp][t][h] = s * (1.0f / N_);
    }
    __syncthreads();

    if (tid < 64) {
        const int grp = tid >> 4;
        const int u = tid & 15;
        const int gbase = tid & ~15;
        const bool active = (grp < 2) && (b0 + grp < B_);
        const int sgrp = active ? grp : 0;

        float whr[GRUH_], whz[GRUH_], whn[GRUH_];
        #pragma unroll
        for (int k = 0; k < GRUH_; ++k) {
            whr[k] = Whh[u * GRUH_ + k];
            whz[k] = Whh[(16 + u) * GRUH_ + k];
            whn[k] = Whh[(32 + u) * GRUH_ + k];
        }
        const float bhr = bhh[u], bhz = bhh[16 + u], bhn = bhh[32 + u];

        float A[3][3], C[3];
        #pragma unroll
        for (int r = 0; r < 3; ++r) {
            const int j = r * 16 + u;
            float cc = bih[j];
            A[r][0] = A[r][1] = A[r][2] = 0.f;
            #pragma unroll
            for (int k = 0; k < HF_; ++k) {
                float wk = Wih[j * HF_ + k];
                cc += wk * gb[k];
                A[r][k >> 3] += wk * Wn[k];
            }
            C[r] = cc;
        }

        float h = 0.f;
        for (int t = 0; t < T_; ++t) {
            float S0 = S2[sgrp][t][0], S1 = S2[sgrp][t][1], Sv2 = S2[sgrp][t][2];
            float gr = C[0] + A[0][0] * S0 + A[0][1] * S1 + A[0][2] * Sv2;
            float gz = C[1] + A[1][0] * S0 + A[1][1] * S1 + A[1][2] * Sv2;
            float gn = C[2] + A[2][0] * S0 + A[2][1] * S1 + A[2][2] * Sv2;
            float hr = bhr, hz = bhz, hn = bhn;
            #pragma unroll
            for (int k = 0; k < GRUH_; ++k) {
                float hk = __shfl(h, gbase + k, 64);
                hr += whr[k] * hk;
                hz += whz[k] * hk;
                hn += whn[k] * hk;
            }
            float r = 1.f / (1.f + __expf(-(gr + hr)));
            float z = 1.f / (1.f + __expf(-(gz + hz)));
            float xa = gn + r * hn;
            float te = __expf(-2.f * xa);
            float nn = (1.f - te) / (1.f + te);     // tanh(xa), fast path
            h = (1.f - z) * nn + z * h;
        }
        if (active) hS[grp][u] = h;
    }
    __syncthreads();

    const int idx = idx0 + tid;
    if (idx < B_ * OUTB_) {
        const int b = idx / OUTB_, o = idx - b * OUTB_;
        const float4* wr = (const float4*)(Wfc + (long)o * GRUH_);
        const float* hr = hS[b - b0];
        float4 w0 = wr[0], w1 = wr[1], w2 = wr[2], w3 = wr[3];
        float acc = bfc[o];
        acc += hr[0]  * w0.x + hr[1]  * w0.y + hr[2]  * w0.z + hr[3]  * w0.w;
        acc += hr[4]  * w1.x + hr[5]  * w1.y + hr[6]  * w1.z + hr[7]  * w1.w;
        acc += hr[8]  * w2.x + hr[9]  * w2.y + hr[10] * w2.z + hr[11] * w2.w;
        acc += hr[12] * w3.x + hr[13] * w3.y + hr[14] * w3.z + hr[15] * w3.w;
        out[idx] = acc;
    }
}

extern "C" void kernel_launch(void* const* d_in, const int* in_sizes, int n_in,
                              void* d_out, int out_size, void* d_ws, size_t ws_size,
                              hipStream_t stream) {
    const float* x    = (const float*)d_in[0];
    const float* ew   = (const float*)d_in[1];
    const float* Wn   = (const float*)d_in[2];
    const float* We   = (const float*)d_in[3];
    const float* al   = (const float*)d_in[4];
    const float* ar   = (const float*)d_in[5];
    const float* ae   = (const float*)d_in[6];
    const float* gb   = (const float*)d_in[7];
    const float* Wih  = (const float*)d_in[8];
    const float* Whh  = (const float*)d_in[9];
    const float* bih  = (const float*)d_in[10];
    const float* bhh  = (const float*)d_in[11];
    const float* Wfc  = (const float*)d_in[12];
    const float* bfc  = (const float*)d_in[13];
    const int*   src  = (const int*)d_in[14];
    const int*   dst  = (const int*)d_in[15];
    float* out = (float*)d_out;

    float* S = (float*)d_ws;                            // [384*3]

    gat_kernel<<<G_, TPB_, 0, stream>>>(x, ew, Wn, We, al, ar, ae, src, dst, S);
    fc_kernel<<<(B_ * OUTB_ + 255) / 256, 256, 0, stream>>>(S, Wn, gb, Wih, bih,
                                                            Whh, bhh, Wfc, bfc, out);
}